// Round 8
// baseline (718.583 us; speedup 1.0000x reference)
//
#include <hip/hip_runtime.h>
#include <hip/hip_bf16.h>

// ---------------------------------------------------------------------------
// UpSampler: rulebook-compacted sparse 3^3 convs (MFMA bf16) + fused tconv+dec
// Voxel occupancy is 4.8% -> only ~2.24 of 27 taps valid per voxel. Convs are
// decomposed into: scatter_k (dense GEMM over compacted per-offset pair lists
// -> fp32 P buffer) + center_k (dense center GEMM + gather-add of P rows).
// ---------------------------------------------------------------------------
#define NC 100000      // N_COARSE
#define MF 400000      // M_FINE
#define K3 27
#define NK 26          // non-center offsets
#define CAPK 8192      // per-offset pair capacity (n_k ~ 4770)
#define CAPR 16        // per-row sparse-neighbor capacity (avg 1.24)

typedef __bf16 bf16_t;
typedef bf16_t bf16x8 __attribute__((ext_vector_type(8)));
typedef bf16_t bf16x4 __attribute__((ext_vector_type(4)));
typedef float  f32x4  __attribute__((ext_vector_type(4)));

// Repacked-weight offsets (elements) inside g_w
#define O_E1 0                       // 27*1*4*512 = 55296
#define O_E2 55296                   // 27*2*4*512 = 110592
#define O_E3 165888                  // 110592
#define O_T  276480                  // 8*2*4*512 = 32768
#define O_D1 309248                  // 2*4*512 = 4096
#define O_D2 313344                  // 2*2*512 = 2048
#define W_TOTAL 315392

__device__ __align__(16) bf16_t g_w[W_TOTAL];
__device__ __align__(16) bf16_t g_x0[(size_t)NC * 32];  // bf16 feats
__device__ __align__(16) bf16_t g_x1[(size_t)NC * 64];
__device__ __align__(16) bf16_t g_x2[(size_t)NC * 64];
__device__ int g_cnt[NK];                               // per-offset pair counts
__device__ int g_pairs[NK * CAPK];                      // per-offset input rows
__device__ int g_pn[NC];                                // per-row #sparse pairs
__device__ int g_pp[(size_t)NC * CAPR];                 // per-row P-row indices
__device__ __align__(16) float g_P[(size_t)NK * CAPK * 64];  // scatter output

static __device__ __forceinline__ bf16x8 zero8() {
    bf16x8 v;
#pragma unroll
    for (int i = 0; i < 8; ++i) v[i] = (bf16_t)0.0f;
    return v;
}

__global__ void zero_k() {
    if (threadIdx.x < NK) g_cnt[threadIdx.x] = 0;
}

// ---------------------------------------------------------------------------
// Fused prep: (a) repack fp32 weights -> bf16 MFMA B-frags; (b) feats fp32 ->
// bf16; (c) build compacted rulebook lists (wave-ballot aggregation: one
// atomicAdd per wave per offset -> no counter contention).
// Blocks [0,154): repack. [154,1717): feats. [1717,2108): rulebook.
// ---------------------------------------------------------------------------
__global__ __launch_bounds__(256) void prep_k(
    const float* __restrict__ W_e1, const float* __restrict__ W_e2,
    const float* __restrict__ W_e3, const float* __restrict__ W_t,
    const float* __restrict__ W_d1, const float* __restrict__ W_d2,
    const float* __restrict__ feats, const int* __restrict__ nbr)
{
    int b = blockIdx.x;
    if (b < 154) {
        int tid = b * 256 + threadIdx.x;
        int lane = tid & 63;
        int f = tid >> 6;            // 0..615
        const float* src; int doff, nt, nc, fb;
        if      (f < 108) { src = W_e1; doff = O_E1; nt = 4; nc = 1; fb = 0;   }
        else if (f < 324) { src = W_e2; doff = O_E2; nt = 4; nc = 2; fb = 108; }
        else if (f < 540) { src = W_e3; doff = O_E3; nt = 4; nc = 2; fb = 324; }
        else if (f < 604) { src = W_t;  doff = O_T;  nt = 4; nc = 2; fb = 540; }
        else if (f < 612) { src = W_d1; doff = O_D1; nt = 4; nc = 2; fb = 604; }
        else              { src = W_d2; doff = O_D2; nt = 2; nc = 2; fb = 612; }
        int lf = f - fb;
        int t  = lf % nt;
        int c  = (lf / nt) % nc;
        int ko = lf / (nt * nc);
        int Cin = nc * 32, Cout = nt * 16;
        int n  = t * 16 + (lane & 15);
        int kb = c * 32 + (lane >> 4) * 8;
        bf16x8 tmp;
#pragma unroll
        for (int j = 0; j < 8; ++j)
            tmp[j] = (bf16_t)src[((size_t)ko * Cin + (kb + j)) * Cout + n];
        *(bf16x8*)(g_w + doff + (size_t)lf * 512 + lane * 8) = tmp;
    } else if (b < 1717) {
        int i = (b - 154) * 256 + threadIdx.x;   // chunk of 8 floats
        if (i < NC * 32 / 8) {
            const f32x4* p = (const f32x4*)(feats + (size_t)i * 8);
            f32x4 lo = p[0], hi = p[1];
            bf16x8 v;
#pragma unroll
            for (int j = 0; j < 4; ++j) { v[j] = (bf16_t)lo[j]; v[j + 4] = (bf16_t)hi[j]; }
            *(bf16x8*)(g_x0 + (size_t)i * 8) = v;
        }
    } else {
        int r = (b - 1717) * 256 + threadIdx.x;
        int lane = threadIdx.x & 63;
        bool rowok = r < NC;
        int c = 0;
        for (int k = 0; k < K3; ++k) {
            if (k == 13) continue;               // center handled densely
            int k26 = k - (k > 13);
            int idx = rowok ? nbr[(size_t)r * K3 + k] : NC;
            bool valid = (unsigned)idx < (unsigned)NC;
            unsigned long long m = __ballot(valid);
            int nv = __popcll(m);
            int base = 0;
            if (lane == 0 && nv) base = atomicAdd(&g_cnt[k26], nv);
            base = __shfl(base, 0, 64);
            if (valid) {
                int p = base + __popcll(m & ((1ull << lane) - 1));
                if (p < CAPK) {
                    g_pairs[k26 * CAPK + p] = idx;
                    if (c < CAPR) g_pp[(size_t)r * CAPR + c] = k26 * CAPK + p;
                    ++c;
                }
            }
        }
        if (rowok) g_pn[r] = (c < CAPR) ? c : CAPR;
    }
}

// ---------------------------------------------------------------------------
// scatter_k: per offset k, dense GEMM over its compacted pair list:
//   P[k][p] = x[pairs[k][p]] @ W[k]   (fp32, no bias, no relu)
// One wave = 64 list entries (4 M-tiles). Grid = 26*128/4 = 832 blocks; waves
// beyond cnt exit immediately (~40% at n_k~4770).
// ---------------------------------------------------------------------------
template <int CH>
__global__ __launch_bounds__(256) void scatter_k(int w_off, int src_sel)
{
    constexpr int CIN = CH * 32;
    const bf16_t* xb = (src_sel == 0) ? g_x0 : (src_sel == 1 ? g_x1 : g_x2);
    int wv = threadIdx.x >> 6, lane = threadIdx.x & 63;
    int cl = lane & 15, q = lane >> 4;
    int wid = blockIdx.x * 4 + wv;
    int k26 = wid >> 7;
    int i0 = (wid & 127) * 64;
    int cnt = g_cnt[k26];
    if (i0 >= cnt) return;
    int kreal = k26 + (k26 >= 13);
    const bf16_t* wre = g_w + w_off + (size_t)kreal * CH * 2048;

    int idx[4];
#pragma unroll
    for (int mt = 0; mt < 4; ++mt) {
        int l = i0 + mt * 16 + cl;
        if (l >= cnt) l = cnt - 1;               // clamp; rows >= cnt not stored
        idx[mt] = g_pairs[k26 * CAPK + l];
    }

    f32x4 acc[4][4];
#pragma unroll
    for (int mt = 0; mt < 4; ++mt)
#pragma unroll
        for (int t = 0; t < 4; ++t) acc[mt][t] = (f32x4){0.f, 0.f, 0.f, 0.f};

#pragma unroll
    for (int c = 0; c < CH; ++c) {
        bf16x8 bfr[4];
#pragma unroll
        for (int t = 0; t < 4; ++t)
            bfr[t] = *(const bf16x8*)(wre + ((size_t)(c * 4 + t)) * 512 + lane * 8);
#pragma unroll
        for (int mt = 0; mt < 4; ++mt) {
            bf16x8 a = *(const bf16x8*)(xb + (size_t)idx[mt] * CIN + c * 32 + q * 8);
#pragma unroll
            for (int t = 0; t < 4; ++t)
                acc[mt][t] = __builtin_amdgcn_mfma_f32_16x16x32_bf16(
                    a, bfr[t], acc[mt][t], 0, 0, 0);
        }
    }

    float* P = g_P + (size_t)k26 * CAPK * 64;
#pragma unroll
    for (int mt = 0; mt < 4; ++mt)
#pragma unroll
        for (int t = 0; t < 4; ++t)
#pragma unroll
            for (int r = 0; r < 4; ++r) {
                int row = i0 + mt * 16 + q * 4 + r;
                if (row < cnt)
                    P[(size_t)row * 64 + t * 16 + cl] = acc[mt][t][r];
            }
}

// ---------------------------------------------------------------------------
// center_k: y[r] = relu( bias + x[r] @ W[13] + sum_j P[pp[r][j]] )
// One wave = 64 rows. Dense center MFMA, fp32 LDS transpose, per-row gather-
// add of its sparse P rows, relu -> bf16 store.
// ---------------------------------------------------------------------------
template <int CH>
__global__ __launch_bounds__(256) void center_k(
    int w_off, const float* __restrict__ bias, int src_sel, int dst_sel)
{
    constexpr int CIN = CH * 32;
    const bf16_t* xb = (src_sel == 0) ? g_x0 : (src_sel == 1 ? g_x1 : g_x2);
    bf16_t* y = (dst_sel == 1) ? g_x1 : g_x2;
    __shared__ __align__(16) float tl[4][32 * 68];   // 8704 B / wave
    int wv = threadIdx.x >> 6, lane = threadIdx.x & 63;
    int cl = lane & 15, q = lane >> 4;
    int base = (blockIdx.x * 4 + wv) * 64;
    if (base >= NC) return;
    const bf16_t* wre = g_w + w_off + (size_t)13 * CH * 2048;

    f32x4 acc[4][4];
#pragma unroll
    for (int t = 0; t < 4; ++t) {
        float b = bias[t * 16 + cl];
#pragma unroll
        for (int mt = 0; mt < 4; ++mt) acc[mt][t] = (f32x4){b, b, b, b};
    }

#pragma unroll
    for (int c = 0; c < CH; ++c) {
        bf16x8 bfr[4];
#pragma unroll
        for (int t = 0; t < 4; ++t)
            bfr[t] = *(const bf16x8*)(wre + ((size_t)(c * 4 + t)) * 512 + lane * 8);
#pragma unroll
        for (int mt = 0; mt < 4; ++mt) {
            int r = base + mt * 16 + cl;
            if (r >= NC) r = NC - 1;             // clamp; results discarded
            bf16x8 a = *(const bf16x8*)(xb + (size_t)r * CIN + c * 32 + q * 8);
#pragma unroll
            for (int t = 0; t < 4; ++t)
                acc[mt][t] = __builtin_amdgcn_mfma_f32_16x16x32_bf16(
                    a, bfr[t], acc[mt][t], 0, 0, 0);
        }
    }

    // per 32-row chunk: fp32 transpose -> sparse adds -> relu -> bf16 store
#pragma unroll
    for (int ch = 0; ch < 2; ++ch) {
#pragma unroll
        for (int mt2 = 0; mt2 < 2; ++mt2)
#pragma unroll
            for (int t = 0; t < 4; ++t)
#pragma unroll
                for (int r = 0; r < 4; ++r)
                    tl[wv][(mt2 * 16 + q * 4 + r) * 68 + t * 16 + cl] =
                        acc[ch * 2 + mt2][t][r];
#pragma unroll
        for (int i = 0; i < 8; ++i) {
            int rl = i * 4 + (lane >> 4);        // 0..31
            int c4 = (lane & 15) * 4;            // 0..60
            int r = base + ch * 32 + rl;
            if (r < NC) {
                f32x4 v = *(const f32x4*)&tl[wv][rl * 68 + c4];
                int n = g_pn[r];
                const int* pp = g_pp + (size_t)r * CAPR;
                for (int j = 0; j < n; ++j) {
                    int pi = pp[j];
                    v += *(const f32x4*)(g_P + (size_t)pi * 64 + c4);
                }
                bf16x4 o;
#pragma unroll
                for (int l = 0; l < 4; ++l) {
                    float x = v[l];
                    o[l] = (bf16_t)(x > 0.0f ? x : 0.0f);
                }
                *(bf16x4*)(y + (size_t)r * 64 + c4) = o;
            }
        }
    }
}

// ---------------------------------------------------------------------------
// Fused tconv + decoder (r6 structure verbatim: VGPR 72, 71 us proven).
// One wave = 16 parents = 64 fine rows. Per-wave LDS, no barriers.
// Grid must be a multiple of 8.
// ---------------------------------------------------------------------------
#define HS 72   // bf16 tile row stride (144 B) == 36-float rows
__global__ __launch_bounds__(256) void tconv_dec_k(
    const int*   __restrict__ offs,   // [MF]
    const float* __restrict__ b_t,
    const float* __restrict__ b_d1,
    const float* __restrict__ b_d2,
    const float* __restrict__ x_up,   // [MF, 32] fp32
    float*       __restrict__ out)    // [MF, 32] fp32
{
    const bf16_t* x3   = g_x1;
    const bf16_t* w_t  = g_w + O_T;
    const bf16_t* w_d1 = g_w + O_D1;
    const bf16_t* w_d2 = g_w + O_D2;

    __shared__ __align__(16) bf16_t h_lds[4][64 * HS];   // 9216 B / wave
    __shared__ __align__(16) int off_lds[4][64];
    int wv = threadIdx.x >> 6, lane = threadIdx.x & 63;
    int cl = lane & 15, q = lane >> 4;
    int per = gridDim.x >> 3;
    int blk = (blockIdx.x & 7) * per + (blockIdx.x >> 3);
    int p0 = (blk * 4 + wv) * 16;
    int fbase = p0 * 4;

    // stage the 64 children's offsets (per-wave)
    {
        int fi = fbase + lane;
        off_lds[wv][lane] = (fi < MF) ? offs[fi] : 0;
    }
    // per-m code: nibble at position k = (child j)+1 where offs[4m+j]==k
    int code[4];
#pragma unroll
    for (int r = 0; r < 4; ++r) {
        int4 o = *(const int4*)&off_lds[wv][(q * 4 + r) * 4];
        code[r] = (1 << (4 * o.x)) | (2 << (4 * o.y)) |
                  (3 << (4 * o.z)) | (4 << (4 * o.w));
    }

    // load X A-frags (parents p0+cl, rows of g_x1)
    bool pv = (p0 + cl) < NC;
    size_t xrow = (size_t)(pv ? p0 + cl : 0) * 64;
    bf16x8 ax[2];
#pragma unroll
    for (int c = 0; c < 2; ++c) {
        bf16x8 t8 = *(const bf16x8*)(x3 + xrow + c * 32 + q * 8);
        ax[c] = pv ? t8 : zero8();
    }

#pragma unroll
    for (int k = 0; k < 8; ++k) {
        f32x4 acc[4];
#pragma unroll
        for (int t = 0; t < 4; ++t) {
            float b = b_t[t * 16 + cl];
            acc[t] = (f32x4){b, b, b, b};
        }
#pragma unroll
        for (int c = 0; c < 2; ++c) {
            const bf16_t* wb = w_t + ((size_t)(k * 2 + c) * 4) * 512 + lane * 8;
#pragma unroll
            for (int t = 0; t < 4; ++t) {
                bf16x8 b = *(const bf16x8*)(wb + t * 512);
                acc[t] = __builtin_amdgcn_mfma_f32_16x16x32_bf16(ax[c], b, acc[t], 0, 0, 0);
            }
        }
        // scatter selected child rows into h1 tile (per-wave)
#pragma unroll
        for (int r = 0; r < 4; ++r) {
            int nib = (code[r] >> (4 * k)) & 0xF;
            if (nib) {
                int fl = (((q * 4 + r) * 4) + (nib - 1)) & 63;
#pragma unroll
                for (int t = 0; t < 4; ++t) {
                    float v = acc[t][r];
                    v = v > 0.0f ? v : 0.0f;
                    h_lds[wv][fl * HS + t * 16 + cl] = (bf16_t)v;
                }
            }
        }
    }

    // ---- decoder stage 1: h2 = relu(h1) @ W_d1 + b_d1 ----
    bf16x8 a1[4][2];
#pragma unroll
    for (int mt = 0; mt < 4; ++mt)
#pragma unroll
        for (int c = 0; c < 2; ++c)
            a1[mt][c] = *(const bf16x8*)&h_lds[wv][(mt * 16 + cl) * HS + c * 32 + q * 8];

#pragma unroll
    for (int mt = 0; mt < 4; ++mt) {
        f32x4 acc2[4];
#pragma unroll
        for (int t = 0; t < 4; ++t) {
            float b = b_d1[t * 16 + cl];
            acc2[t] = (f32x4){b, b, b, b};
        }
#pragma unroll
        for (int c = 0; c < 2; ++c)
#pragma unroll
            for (int t = 0; t < 4; ++t) {
                bf16x8 b = *(const bf16x8*)(w_d1 + (size_t)(c * 4 + t) * 512 + lane * 8);
                acc2[t] = __builtin_amdgcn_mfma_f32_16x16x32_bf16(a1[mt][c], b, acc2[t], 0, 0, 0);
            }
#pragma unroll
        for (int t = 0; t < 4; ++t)
#pragma unroll
            for (int r = 0; r < 4; ++r) {
                float v = acc2[t][r];
                v = v > 0.0f ? v : 0.0f;
                h_lds[wv][(mt * 16 + q * 4 + r) * HS + t * 16 + cl] = (bf16_t)v;
            }
    }

    // ---- decoder stage 2: h3 = relu(h2) @ W_d2 + b_d2, fp32 into same rows --
    float* fW = (float*)h_lds[wv];
#pragma unroll
    for (int mt = 0; mt < 4; ++mt) {
        bf16x8 a2[2];
#pragma unroll
        for (int c = 0; c < 2; ++c)
            a2[c] = *(const bf16x8*)&h_lds[wv][(mt * 16 + cl) * HS + c * 32 + q * 8];
        f32x4 acc3[2];
#pragma unroll
        for (int t = 0; t < 2; ++t) {
            float b = b_d2[t * 16 + cl];
            acc3[t] = (f32x4){b, b, b, b};
        }
#pragma unroll
        for (int c = 0; c < 2; ++c)
#pragma unroll
            for (int t = 0; t < 2; ++t) {
                bf16x8 b = *(const bf16x8*)(w_d2 + (size_t)(c * 2 + t) * 512 + lane * 8);
                acc3[t] = __builtin_amdgcn_mfma_f32_16x16x32_bf16(a2[c], b, acc3[t], 0, 0, 0);
            }
#pragma unroll
        for (int t = 0; t < 2; ++t)
#pragma unroll
            for (int r = 0; r < 4; ++r)
                fW[(mt * 16 + q * 4 + r) * 36 + t * 16 + cl] = acc3[t][r];
    }

    // ---- coalesced epilogue: out = h3 + x_up (float4/lane) ----
#pragma unroll
    for (int i = 0; i < 8; ++i) {
        int rl = i * 8 + (lane >> 3);
        int c4 = (lane & 7) * 4;
        int fg = fbase + rl;
        if (fg < MF) {
            f32x4 xv = *(const f32x4*)(x_up + (size_t)fg * 32 + c4);
            f32x4 v = *(const f32x4*)&fW[rl * 36 + c4];
            v += xv;
            *(f32x4*)(out + (size_t)fg * 32 + c4) = v;
        }
    }
}

// ---------------------------------------------------------------------------
extern "C" void kernel_launch(void* const* d_in, const int* in_sizes, int n_in,
                              void* d_out, int out_size, void* d_ws, size_t ws_size,
                              hipStream_t stream) {
    const float* feats  = (const float*)d_in[0];
    const float* x_up   = (const float*)d_in[1];
    const int*   nbr    = (const int*)d_in[2];
    const int*   offs   = (const int*)d_in[4];
    const float* W_e1 = (const float*)d_in[5];
    const float* b_e1 = (const float*)d_in[6];
    const float* W_e2 = (const float*)d_in[7];
    const float* b_e2 = (const float*)d_in[8];
    const float* W_e3 = (const float*)d_in[9];
    const float* b_e3 = (const float*)d_in[10];
    const float* W_t  = (const float*)d_in[11];
    const float* b_t  = (const float*)d_in[12];
    const float* W_d1 = (const float*)d_in[13];
    const float* b_d1 = (const float*)d_in[14];
    const float* W_d2 = (const float*)d_in[15];
    const float* b_d2 = (const float*)d_in[16];
    float* out = (float*)d_out;

    zero_k<<<1, 64, 0, stream>>>();
    // prep: 154 repack + 1563 feats + 391 rulebook blocks
    prep_k<<<2108, 256, 0, stream>>>(W_e1, W_e2, W_e3, W_t, W_d1, W_d2, feats, nbr);

    // layer 1 (Cin=32): g_x0 -> g_x1
    scatter_k<1><<<832, 256, 0, stream>>>(O_E1, 0);
    center_k<1><<<391, 256, 0, stream>>>(O_E1, b_e1, 0, 1);
    // layer 2: g_x1 -> g_x2
    scatter_k<2><<<832, 256, 0, stream>>>(O_E2, 1);
    center_k<2><<<391, 256, 0, stream>>>(O_E2, b_e2, 1, 2);
    // layer 3: g_x2 -> g_x1
    scatter_k<2><<<832, 256, 0, stream>>>(O_E3, 2);
    center_k<2><<<391, 256, 0, stream>>>(O_E3, b_e3, 2, 1);

    // tconv+decoder: 16 parents/wave -> ceil(6250/4)=1563 -> pad 1568 (x8)
    tconv_dec_k<<<1568, 256, 0, stream>>>(offs, b_t, b_d1, b_d2, x_up, out);
}

// Round 9
// 393.105 us; speedup vs baseline: 1.8280x; 1.8280x over previous
//
#include <hip/hip_runtime.h>
#include <hip/hip_bf16.h>

// ---------------------------------------------------------------------------
// UpSampler: rulebook-compacted sparse 3^3 convs (MFMA bf16) + fused tconv+dec
// 4.8% voxel occupancy -> ~2.24 of 27 taps valid. Convs = scatter_k (dense
// GEMM over compacted per-offset lists -> fp32 P) + center_k (dense center
// GEMM + gather-add of P rows). Compaction is ATOMIC-FREE (r8 lesson: the
// per-offset atomicAdd convoy cost 380 us): count -> scan -> fill.
// ---------------------------------------------------------------------------
#define NC 100000      // N_COARSE
#define MF 400000      // M_FINE
#define K3 27
#define NK 26          // non-center offsets
#define CAPK 8192      // per-offset pair capacity (n_k ~ 4770)
#define CAPR 16        // per-row sparse-neighbor capacity (avg ~1.24)
#define NWV 1564       // wave-slots covering NC rows (1564*64 >= 100000)
#define NWPAD 1600

typedef __bf16 bf16_t;
typedef bf16_t bf16x8 __attribute__((ext_vector_type(8)));
typedef bf16_t bf16x4 __attribute__((ext_vector_type(4)));
typedef float  f32x4  __attribute__((ext_vector_type(4)));

// Repacked-weight offsets (elements) inside g_w
#define O_E1 0                       // 27*1*4*512 = 55296
#define O_E2 55296                   // 27*2*4*512 = 110592
#define O_E3 165888                  // 110592
#define O_T  276480                  // 8*2*4*512 = 32768
#define O_D1 309248                  // 2*4*512 = 4096
#define O_D2 313344                  // 2*2*512 = 2048
#define W_TOTAL 315392

__device__ __align__(16) bf16_t g_w[W_TOTAL];
__device__ __align__(16) bf16_t g_x0[(size_t)NC * 32];  // bf16 feats
__device__ __align__(16) bf16_t g_x1[(size_t)NC * 64];
__device__ __align__(16) bf16_t g_x2[(size_t)NC * 64];
__device__ int g_wcnt[NK * NWPAD];                      // per-(offset,wave) counts
__device__ int g_wbase[NK * NWPAD];                     // exclusive bases
__device__ int g_cnt[NK];                               // per-offset totals
__device__ int g_pairs[NK * CAPK];                      // per-offset input rows
__device__ int g_pn[NC];                                // per-row #sparse pairs
__device__ int g_pp[(size_t)NC * CAPR];                 // per-row P-row indices
__device__ __align__(16) float g_P[(size_t)NK * CAPK * 64];  // scatter output

static __device__ __forceinline__ bf16x8 zero8() {
    bf16x8 v;
#pragma unroll
    for (int i = 0; i < 8; ++i) v[i] = (bf16_t)0.0f;
    return v;
}

// ---------------------------------------------------------------------------
// prep1: (a) repack fp32 weights -> bf16 MFMA B-frags; (b) feats fp32->bf16;
// (c) per-wave valid counts per offset (NO atomics, one store/wave/offset).
// Blocks [0,154): repack. [154,1717): feats. [1717,2108): counts.
// ---------------------------------------------------------------------------
__global__ __launch_bounds__(256) void prep1_k(
    const float* __restrict__ W_e1, const float* __restrict__ W_e2,
    const float* __restrict__ W_e3, const float* __restrict__ W_t,
    const float* __restrict__ W_d1, const float* __restrict__ W_d2,
    const float* __restrict__ feats, const int* __restrict__ nbr)
{
    int b = blockIdx.x;
    if (b < 154) {
        int tid = b * 256 + threadIdx.x;
        int lane = tid & 63;
        int f = tid >> 6;            // 0..615
        const float* src; int doff, nt, nc, fb;
        if      (f < 108) { src = W_e1; doff = O_E1; nt = 4; nc = 1; fb = 0;   }
        else if (f < 324) { src = W_e2; doff = O_E2; nt = 4; nc = 2; fb = 108; }
        else if (f < 540) { src = W_e3; doff = O_E3; nt = 4; nc = 2; fb = 324; }
        else if (f < 604) { src = W_t;  doff = O_T;  nt = 4; nc = 2; fb = 540; }
        else if (f < 612) { src = W_d1; doff = O_D1; nt = 4; nc = 2; fb = 604; }
        else              { src = W_d2; doff = O_D2; nt = 2; nc = 2; fb = 612; }
        int lf = f - fb;
        int t  = lf % nt;
        int c  = (lf / nt) % nc;
        int ko = lf / (nt * nc);
        int Cin = nc * 32, Cout = nt * 16;
        int n  = t * 16 + (lane & 15);
        int kb = c * 32 + (lane >> 4) * 8;
        bf16x8 tmp;
#pragma unroll
        for (int j = 0; j < 8; ++j)
            tmp[j] = (bf16_t)src[((size_t)ko * Cin + (kb + j)) * Cout + n];
        *(bf16x8*)(g_w + doff + (size_t)lf * 512 + lane * 8) = tmp;
    } else if (b < 1717) {
        int i = (b - 154) * 256 + threadIdx.x;   // chunk of 8 floats
        if (i < NC * 32 / 8) {
            const f32x4* p = (const f32x4*)(feats + (size_t)i * 8);
            f32x4 lo = p[0], hi = p[1];
            bf16x8 v;
#pragma unroll
            for (int j = 0; j < 4; ++j) { v[j] = (bf16_t)lo[j]; v[j + 4] = (bf16_t)hi[j]; }
            *(bf16x8*)(g_x0 + (size_t)i * 8) = v;
        }
    } else {
        int wv = threadIdx.x >> 6, lane = threadIdx.x & 63;
        int wblk = (b - 1717) * 4 + wv;          // 0..1563
        int r = wblk * 64 + lane;
        bool rowok = r < NC;
        for (int k = 0; k < K3; ++k) {
            if (k == 13) continue;
            int k26 = k - (k > 13);
            int idx = rowok ? nbr[(size_t)r * K3 + k] : NC;
            bool valid = (unsigned)idx < (unsigned)NC;
            unsigned long long m = __ballot(valid);
            if (lane == 0) g_wcnt[k26 * NWPAD + wblk] = __popcll(m);
        }
    }
}

// ---------------------------------------------------------------------------
// prep2: per offset k (26 blocks, 1 wave each): exclusive scan of the 1564
// wave counts -> g_wbase, total -> g_cnt. Shuffle-based, contention-free.
// ---------------------------------------------------------------------------
__global__ __launch_bounds__(64) void prep2_k() {
    int k = blockIdx.x, lane = threadIdx.x;
    int run = 0;
    for (int i0 = 0; i0 < NWV; i0 += 64) {
        int i = i0 + lane;
        int v = (i < NWV) ? g_wcnt[k * NWPAD + i] : 0;
        int s = v;
#pragma unroll
        for (int d = 1; d < 64; d <<= 1) {
            int t = __shfl_up(s, d, 64);
            if (lane >= d) s += t;
        }
        if (i < NWV) g_wbase[k * NWPAD + i] = run + s - v;
        run += __shfl(s, 63, 64);
    }
    if (lane == 0) g_cnt[k] = run;
}

// ---------------------------------------------------------------------------
// prep3: recompute ballots, write pair lists + per-row P indices at the
// deterministic positions from g_wbase. 391 blocks x 256.
// ---------------------------------------------------------------------------
__global__ __launch_bounds__(256) void prep3_k(const int* __restrict__ nbr) {
    int wv = threadIdx.x >> 6, lane = threadIdx.x & 63;
    int wblk = blockIdx.x * 4 + wv;
    int r = wblk * 64 + lane;
    bool rowok = r < NC;
    int c = 0;
    for (int k = 0; k < K3; ++k) {
        if (k == 13) continue;
        int k26 = k - (k > 13);
        int idx = rowok ? nbr[(size_t)r * K3 + k] : NC;
        bool valid = (unsigned)idx < (unsigned)NC;
        unsigned long long m = __ballot(valid);
        if (valid) {
            int p = g_wbase[k26 * NWPAD + wblk] + __popcll(m & ((1ull << lane) - 1));
            g_pairs[k26 * CAPK + p] = idx;
            if (c < CAPR) g_pp[(size_t)r * CAPR + c] = k26 * CAPK + p;
            ++c;
        }
    }
    if (rowok) g_pn[r] = (c < CAPR) ? c : CAPR;
}

// ---------------------------------------------------------------------------
// scatter_k: per offset k, dense GEMM over its compacted list:
//   P[k][p] = x[pairs[k][p]] @ W[k]   (fp32, no bias/relu)
// One wave = 64 entries. Epilogue: fp32 LDS transpose -> coalesced f32x4
// stores (r8 lesson: 64 scalar dword stores/lane was the scalar-store bug).
// ---------------------------------------------------------------------------
template <int CH>
__global__ __launch_bounds__(256) void scatter_k(int w_off, int src_sel)
{
    constexpr int CIN = CH * 32;
    const bf16_t* xb = (src_sel == 0) ? g_x0 : (src_sel == 1 ? g_x1 : g_x2);
    __shared__ __align__(16) float tl[4][32 * 68];
    int wv = threadIdx.x >> 6, lane = threadIdx.x & 63;
    int cl = lane & 15, q = lane >> 4;
    int wid = blockIdx.x * 4 + wv;
    int k26 = wid >> 7;
    int i0 = (wid & 127) * 64;
    int cnt = g_cnt[k26];
    if (i0 >= cnt) return;
    int kreal = k26 + (k26 >= 13);
    const bf16_t* wre = g_w + w_off + (size_t)kreal * CH * 2048;

    int idx[4];
#pragma unroll
    for (int mt = 0; mt < 4; ++mt) {
        int l = i0 + mt * 16 + cl;
        if (l >= cnt) l = cnt - 1;               // clamp; rows >= cnt not stored
        idx[mt] = g_pairs[k26 * CAPK + l];
    }

    f32x4 acc[4][4];
#pragma unroll
    for (int mt = 0; mt < 4; ++mt)
#pragma unroll
        for (int t = 0; t < 4; ++t) acc[mt][t] = (f32x4){0.f, 0.f, 0.f, 0.f};

#pragma unroll
    for (int c = 0; c < CH; ++c) {
        bf16x8 bfr[4];
#pragma unroll
        for (int t = 0; t < 4; ++t)
            bfr[t] = *(const bf16x8*)(wre + ((size_t)(c * 4 + t)) * 512 + lane * 8);
#pragma unroll
        for (int mt = 0; mt < 4; ++mt) {
            bf16x8 a = *(const bf16x8*)(xb + (size_t)idx[mt] * CIN + c * 32 + q * 8);
#pragma unroll
            for (int t = 0; t < 4; ++t)
                acc[mt][t] = __builtin_amdgcn_mfma_f32_16x16x32_bf16(
                    a, bfr[t], acc[mt][t], 0, 0, 0);
        }
    }

    float* P = g_P + (size_t)k26 * CAPK * 64;
#pragma unroll
    for (int ch = 0; ch < 2; ++ch) {
#pragma unroll
        for (int mt2 = 0; mt2 < 2; ++mt2)
#pragma unroll
            for (int t = 0; t < 4; ++t)
#pragma unroll
                for (int r = 0; r < 4; ++r)
                    tl[wv][(mt2 * 16 + q * 4 + r) * 68 + t * 16 + cl] =
                        acc[ch * 2 + mt2][t][r];
#pragma unroll
        for (int i = 0; i < 8; ++i) {
            int rl = i * 4 + (lane >> 4);        // 0..31
            int c4 = (lane & 15) * 4;
            int row = i0 + ch * 32 + rl;
            if (row < cnt)
                *(f32x4*)(P + (size_t)row * 64 + c4) = *(const f32x4*)&tl[wv][rl * 68 + c4];
        }
    }
}

// ---------------------------------------------------------------------------
// center_k: y[r] = relu( bias + x[r] @ W[13] + sum_j P[pp[r][j]] )
// One wave = 64 rows; dense MFMA, fp32 LDS transpose, sparse P adds.
// ---------------------------------------------------------------------------
template <int CH>
__global__ __launch_bounds__(256) void center_k(
    int w_off, const float* __restrict__ bias, int src_sel, int dst_sel)
{
    constexpr int CIN = CH * 32;
    const bf16_t* xb = (src_sel == 0) ? g_x0 : (src_sel == 1 ? g_x1 : g_x2);
    bf16_t* y = (dst_sel == 1) ? g_x1 : g_x2;
    __shared__ __align__(16) float tl[4][32 * 68];   // 8704 B / wave
    int wv = threadIdx.x >> 6, lane = threadIdx.x & 63;
    int cl = lane & 15, q = lane >> 4;
    int base = (blockIdx.x * 4 + wv) * 64;
    if (base >= NC) return;
    const bf16_t* wre = g_w + w_off + (size_t)13 * CH * 2048;

    f32x4 acc[4][4];
#pragma unroll
    for (int t = 0; t < 4; ++t) {
        float b = bias[t * 16 + cl];
#pragma unroll
        for (int mt = 0; mt < 4; ++mt) acc[mt][t] = (f32x4){b, b, b, b};
    }

#pragma unroll
    for (int c = 0; c < CH; ++c) {
        bf16x8 bfr[4];
#pragma unroll
        for (int t = 0; t < 4; ++t)
            bfr[t] = *(const bf16x8*)(wre + ((size_t)(c * 4 + t)) * 512 + lane * 8);
#pragma unroll
        for (int mt = 0; mt < 4; ++mt) {
            int r = base + mt * 16 + cl;
            if (r >= NC) r = NC - 1;             // clamp; results discarded
            bf16x8 a = *(const bf16x8*)(xb + (size_t)r * CIN + c * 32 + q * 8);
#pragma unroll
            for (int t = 0; t < 4; ++t)
                acc[mt][t] = __builtin_amdgcn_mfma_f32_16x16x32_bf16(
                    a, bfr[t], acc[mt][t], 0, 0, 0);
        }
    }

#pragma unroll
    for (int ch = 0; ch < 2; ++ch) {
#pragma unroll
        for (int mt2 = 0; mt2 < 2; ++mt2)
#pragma unroll
            for (int t = 0; t < 4; ++t)
#pragma unroll
                for (int r = 0; r < 4; ++r)
                    tl[wv][(mt2 * 16 + q * 4 + r) * 68 + t * 16 + cl] =
                        acc[ch * 2 + mt2][t][r];
#pragma unroll
        for (int i = 0; i < 8; ++i) {
            int rl = i * 4 + (lane >> 4);        // 0..31
            int c4 = (lane & 15) * 4;            // 0..60
            int r = base + ch * 32 + rl;
            if (r < NC) {
                f32x4 v = *(const f32x4*)&tl[wv][rl * 68 + c4];
                int n = g_pn[r];
                const int* pp = g_pp + (size_t)r * CAPR;
                for (int j = 0; j < n; ++j) {
                    int pi = pp[j];
                    v += *(const f32x4*)(g_P + (size_t)pi * 64 + c4);
                }
                bf16x4 o;
#pragma unroll
                for (int l = 0; l < 4; ++l) {
                    float x = v[l];
                    o[l] = (bf16_t)(x > 0.0f ? x : 0.0f);
                }
                *(bf16x4*)(y + (size_t)r * 64 + c4) = o;
            }
        }
    }
}

// ---------------------------------------------------------------------------
// Fused tconv + decoder (r6 structure verbatim: VGPR 72, 71 us proven).
// One wave = 16 parents = 64 fine rows. Per-wave LDS, no barriers.
// Grid must be a multiple of 8.
// ---------------------------------------------------------------------------
#define HS 72   // bf16 tile row stride (144 B) == 36-float rows
__global__ __launch_bounds__(256) void tconv_dec_k(
    const int*   __restrict__ offs,   // [MF]
    const float* __restrict__ b_t,
    const float* __restrict__ b_d1,
    const float* __restrict__ b_d2,
    const float* __restrict__ x_up,   // [MF, 32] fp32
    float*       __restrict__ out)    // [MF, 32] fp32
{
    const bf16_t* x3   = g_x1;
    const bf16_t* w_t  = g_w + O_T;
    const bf16_t* w_d1 = g_w + O_D1;
    const bf16_t* w_d2 = g_w + O_D2;

    __shared__ __align__(16) bf16_t h_lds[4][64 * HS];   // 9216 B / wave
    __shared__ __align__(16) int off_lds[4][64];
    int wv = threadIdx.x >> 6, lane = threadIdx.x & 63;
    int cl = lane & 15, q = lane >> 4;
    int per = gridDim.x >> 3;
    int blk = (blockIdx.x & 7) * per + (blockIdx.x >> 3);
    int p0 = (blk * 4 + wv) * 16;
    int fbase = p0 * 4;

    {
        int fi = fbase + lane;
        off_lds[wv][lane] = (fi < MF) ? offs[fi] : 0;
    }
    int code[4];
#pragma unroll
    for (int r = 0; r < 4; ++r) {
        int4 o = *(const int4*)&off_lds[wv][(q * 4 + r) * 4];
        code[r] = (1 << (4 * o.x)) | (2 << (4 * o.y)) |
                  (3 << (4 * o.z)) | (4 << (4 * o.w));
    }

    bool pv = (p0 + cl) < NC;
    size_t xrow = (size_t)(pv ? p0 + cl : 0) * 64;
    bf16x8 ax[2];
#pragma unroll
    for (int c = 0; c < 2; ++c) {
        bf16x8 t8 = *(const bf16x8*)(x3 + xrow + c * 32 + q * 8);
        ax[c] = pv ? t8 : zero8();
    }

#pragma unroll
    for (int k = 0; k < 8; ++k) {
        f32x4 acc[4];
#pragma unroll
        for (int t = 0; t < 4; ++t) {
            float b = b_t[t * 16 + cl];
            acc[t] = (f32x4){b, b, b, b};
        }
#pragma unroll
        for (int c = 0; c < 2; ++c) {
            const bf16_t* wb = w_t + ((size_t)(k * 2 + c) * 4) * 512 + lane * 8;
#pragma unroll
            for (int t = 0; t < 4; ++t) {
                bf16x8 b = *(const bf16x8*)(wb + t * 512);
                acc[t] = __builtin_amdgcn_mfma_f32_16x16x32_bf16(ax[c], b, acc[t], 0, 0, 0);
            }
        }
#pragma unroll
        for (int r = 0; r < 4; ++r) {
            int nib = (code[r] >> (4 * k)) & 0xF;
            if (nib) {
                int fl = (((q * 4 + r) * 4) + (nib - 1)) & 63;
#pragma unroll
                for (int t = 0; t < 4; ++t) {
                    float v = acc[t][r];
                    v = v > 0.0f ? v : 0.0f;
                    h_lds[wv][fl * HS + t * 16 + cl] = (bf16_t)v;
                }
            }
        }
    }

    bf16x8 a1[4][2];
#pragma unroll
    for (int mt = 0; mt < 4; ++mt)
#pragma unroll
        for (int c = 0; c < 2; ++c)
            a1[mt][c] = *(const bf16x8*)&h_lds[wv][(mt * 16 + cl) * HS + c * 32 + q * 8];

#pragma unroll
    for (int mt = 0; mt < 4; ++mt) {
        f32x4 acc2[4];
#pragma unroll
        for (int t = 0; t < 4; ++t) {
            float b = b_d1[t * 16 + cl];
            acc2[t] = (f32x4){b, b, b, b};
        }
#pragma unroll
        for (int c = 0; c < 2; ++c)
#pragma unroll
            for (int t = 0; t < 4; ++t) {
                bf16x8 b = *(const bf16x8*)(w_d1 + (size_t)(c * 4 + t) * 512 + lane * 8);
                acc2[t] = __builtin_amdgcn_mfma_f32_16x16x32_bf16(a1[mt][c], b, acc2[t], 0, 0, 0);
            }
#pragma unroll
        for (int t = 0; t < 4; ++t)
#pragma unroll
            for (int r = 0; r < 4; ++r) {
                float v = acc2[t][r];
                v = v > 0.0f ? v : 0.0f;
                h_lds[wv][(mt * 16 + q * 4 + r) * HS + t * 16 + cl] = (bf16_t)v;
            }
    }

    float* fW = (float*)h_lds[wv];
#pragma unroll
    for (int mt = 0; mt < 4; ++mt) {
        bf16x8 a2[2];
#pragma unroll
        for (int c = 0; c < 2; ++c)
            a2[c] = *(const bf16x8*)&h_lds[wv][(mt * 16 + cl) * HS + c * 32 + q * 8];
        f32x4 acc3[2];
#pragma unroll
        for (int t = 0; t < 2; ++t) {
            float b = b_d2[t * 16 + cl];
            acc3[t] = (f32x4){b, b, b, b};
        }
#pragma unroll
        for (int c = 0; c < 2; ++c)
#pragma unroll
            for (int t = 0; t < 2; ++t) {
                bf16x8 b = *(const bf16x8*)(w_d2 + (size_t)(c * 2 + t) * 512 + lane * 8);
                acc3[t] = __builtin_amdgcn_mfma_f32_16x16x32_bf16(a2[c], b, acc3[t], 0, 0, 0);
            }
#pragma unroll
        for (int t = 0; t < 2; ++t)
#pragma unroll
            for (int r = 0; r < 4; ++r)
                fW[(mt * 16 + q * 4 + r) * 36 + t * 16 + cl] = acc3[t][r];
    }

#pragma unroll
    for (int i = 0; i < 8; ++i) {
        int rl = i * 8 + (lane >> 3);
        int c4 = (lane & 7) * 4;
        int fg = fbase + rl;
        if (fg < MF) {
            f32x4 xv = *(const f32x4*)(x_up + (size_t)fg * 32 + c4);
            f32x4 v = *(const f32x4*)&fW[rl * 36 + c4];
            v += xv;
            *(f32x4*)(out + (size_t)fg * 32 + c4) = v;
        }
    }
}

// ---------------------------------------------------------------------------
extern "C" void kernel_launch(void* const* d_in, const int* in_sizes, int n_in,
                              void* d_out, int out_size, void* d_ws, size_t ws_size,
                              hipStream_t stream) {
    const float* feats  = (const float*)d_in[0];
    const float* x_up   = (const float*)d_in[1];
    const int*   nbr    = (const int*)d_in[2];
    const int*   offs   = (const int*)d_in[4];
    const float* W_e1 = (const float*)d_in[5];
    const float* b_e1 = (const float*)d_in[6];
    const float* W_e2 = (const float*)d_in[7];
    const float* b_e2 = (const float*)d_in[8];
    const float* W_e3 = (const float*)d_in[9];
    const float* b_e3 = (const float*)d_in[10];
    const float* W_t  = (const float*)d_in[11];
    const float* b_t  = (const float*)d_in[12];
    const float* W_d1 = (const float*)d_in[13];
    const float* b_d1 = (const float*)d_in[14];
    const float* W_d2 = (const float*)d_in[15];
    const float* b_d2 = (const float*)d_in[16];
    float* out = (float*)d_out;

    // atomic-free compaction: count -> scan -> fill
    prep1_k<<<2108, 256, 0, stream>>>(W_e1, W_e2, W_e3, W_t, W_d1, W_d2, feats, nbr);
    prep2_k<<<26, 64, 0, stream>>>();
    prep3_k<<<391, 256, 0, stream>>>(nbr);

    // layer 1 (Cin=32): g_x0 -> g_x1
    scatter_k<1><<<832, 256, 0, stream>>>(O_E1, 0);
    center_k<1><<<391, 256, 0, stream>>>(O_E1, b_e1, 0, 1);
    // layer 2: g_x1 -> g_x2
    scatter_k<2><<<832, 256, 0, stream>>>(O_E2, 1);
    center_k<2><<<391, 256, 0, stream>>>(O_E2, b_e2, 1, 2);
    // layer 3: g_x2 -> g_x1
    scatter_k<2><<<832, 256, 0, stream>>>(O_E3, 2);
    center_k<2><<<391, 256, 0, stream>>>(O_E3, b_e3, 2, 1);

    // tconv+decoder: 16 parents/wave -> ceil(6250/4)=1563 -> pad 1568 (x8)
    tconv_dec_k<<<1568, 256, 0, stream>>>(offs, b_t, b_d1, b_d2, x_up, out);
}